// Round 7
// baseline (95.912 us; speedup 1.0000x reference)
//
#include <hip/hip_runtime.h>

#define A_N 120000
#define B_N 8
#define M_N 64
#define APT 2                       // anchors per thread
#define TPB 256
#define GX  ((A_N + TPB*APT - 1) / (TPB*APT))   // 235 blocks in x

#define K_LIST(X) X(0) X(1)

// ---------------------------------------------------------------------------
// Main kernel: each thread owns 2 anchors; each anchor tracks its IoU-argmax
// in TWO independent chains (even/odd GT indices) merged at the end -> 4
// independent dep chains per thread, halved serial latency per GT.
// Division-free cross-mult compares throughout; first-max tie rule preserved.
// ---------------------------------------------------------------------------
__global__ __launch_bounds__(TPB, 4) void retina_main(
    const float* __restrict__ yt,       // (B, M, 5)  cx,cy,w,h,label
    const float* __restrict__ ycls,     // (B, A, 1)
    const float* __restrict__ yreg,     // (B, A, 4)
    const float* __restrict__ anchors,  // (A, 4)     x1,y1,x2,y2
    float* __restrict__ ws_cls,         // [B*GX] partial cls sums
    float* __restrict__ ws_reg,         // [B*GX] partial reg sums
    int*   __restrict__ ws_pos)         // [B*GX] partial pos counts
{
    __shared__ float4 s_box[M_N];   // gt corners
    __shared__ float  s_area[M_N];  // gt area
    __shared__ float4 s_raw[M_N];   // raw cx,cy,w,h
    __shared__ float  s_lab[M_N];   // label
    __shared__ float  s_rc[4], s_rr[4];
    __shared__ int    s_rp[4];
    __shared__ int    s_ngt;

    const int b   = blockIdx.y;
    const int tid = threadIdx.x;
    const int a0  = blockIdx.x * (TPB * APT) + tid;   // + k*TPB

    if (tid < M_N) {                 // exactly wave 0, all 64 lanes active
        const float* g = yt + (b * M_N + tid) * 5;
        float cx = g[0], cy = g[1], w = g[2], h = g[3], lab = g[4];
        float x1 = cx - 0.5f * w, y1 = cy - 0.5f * h;
        float x2 = cx + 0.5f * w, y2 = cy + 0.5f * h;
        s_box[tid]  = make_float4(x1, y1, x2, y2);
        s_area[tid] = (x2 - x1) * (y2 - y1);
        s_raw[tid]  = make_float4(cx, cy, w, h);
        s_lab[tid]  = lab;
        // valid GTs are a prefix; count them (wave-uniform loop bound)
        unsigned long long mv = __ballot(lab != -1.0f);
        if (tid == 0) s_ngt = (int)__popcll(mv);
    }
    __syncthreads();
    const int ngt = s_ngt;           // >= 1 always

    // ---- per-anchor state: named scalars only (no arrays -> no scratch) ----
#define DECL(k) float ax1_##k, ay1_##k, ax2_##k, ay2_##k, sa_##k, pp_##k; \
                float biA_##k, bdA_##k, biB_##k, bdB_##k; \
                int   baA_##k, baB_##k;
    K_LIST(DECL)
#undef DECL

#define INIT(k) { \
        int a  = a0 + (k) * TPB; \
        int ac = (a < A_N) ? a : (A_N - 1); \
        float4 an = *reinterpret_cast<const float4*>(anchors + (size_t)ac * 4); \
        ax1_##k = an.x; ay1_##k = an.y; ax2_##k = an.z; ay2_##k = an.w; \
        sa_##k  = (an.z - an.x) * (an.w - an.y); \
        pp_##k  = ycls[(size_t)b * A_N + ac]; \
        biA_##k = -1.0f; bdA_##k = 1.0f; baA_##k = 0; \
        biB_##k = -1.0f; bdB_##k = 1.0f; baB_##k = 0; }
    K_LIST(INIT)
#undef INIT

    // generic step: updates chain (bi,bd,ba) of anchor k from box (bx,ar,gi)
#define STEPC(k, bi, bd, ba, bx, ar, gi) { \
        float w = fminf(ax2_##k, bx.z) - fmaxf(ax1_##k, bx.x); \
        float h = fminf(ay2_##k, bx.w) - fmaxf(ay1_##k, bx.y); \
        float inter = fmaxf(w, 0.0f) * fmaxf(h, 0.0f); \
        float denom = (sa_##k + ar) - inter; \
        bool better = inter * bd##_##k > bi##_##k * denom; \
        bi##_##k = better ? inter : bi##_##k; \
        bd##_##k = better ? denom : bd##_##k; \
        ba##_##k = better ? (gi)  : ba##_##k; }

    // ---- inner loop over valid GT prefix, 2 GTs per iteration ----
    int g = 0;
    #pragma unroll 2
    for (; g + 1 < ngt; g += 2) {
        const float4 gbA = s_box[g];
        const float  gaA = s_area[g];
        const float4 gbB = s_box[g + 1];
        const float  gaB = s_area[g + 1];
        STEPC(0, biA, bdA, baA, gbA, gaA, g)
        STEPC(1, biA, bdA, baA, gbA, gaA, g)
        STEPC(0, biB, bdB, baB, gbB, gaB, g + 1)
        STEPC(1, biB, bdB, baB, gbB, gaB, g + 1)
    }
    if (g < ngt) {                   // odd ngt tail -> chain A
        const float4 gbA = s_box[g];
        const float  gaA = s_area[g];
        STEPC(0, biA, bdA, baA, gbA, gaA, g)
        STEPC(1, biA, bdA, baA, gbA, gaA, g)
    }
#undef STEPC

    // ---- per-anchor tail: merge chains, focal cls + smooth-L1 reg ----
    float clsv = 0.0f, regv = 0.0f;
    int   posn = 0;
#define TAIL(k) { \
        int a = a0 + (k) * TPB; \
        if (a < A_N) { \
            /* merge: ratio_B > ratio_A, or exact tie -> smaller index first */ \
            float cA = biA_##k * bdB_##k; \
            float cB = biB_##k * bdA_##k; \
            bool pickB = (cB > cA) || ((cB == cA) && (baB_##k < baA_##k)); \
            float bi = pickB ? biB_##k : biA_##k; \
            float bd = pickB ? bdB_##k : bdA_##k; \
            int   ba = pickB ? baB_##k : baA_##k; \
            const bool pos = (bi >= 0.5f * bd); \
            const bool neg = (bi <  0.4f * bd); \
            posn += pos ? 1 : 0; \
            const float p = pp_##k; \
            float target; \
            if (pos) { \
                int alab = (int)s_lab[ba]; \
                target = (alab == 0) ? 1.0f : 0.0f; \
            } else { \
                target = neg ? 0.0f : -1.0f; \
            } \
            if (target == 1.0f) { \
                float fw = 1.0f - p; \
                clsv += 0.25f * fw * fw * (-logf(p)); \
            } else if (target == 0.0f) { \
                clsv += 0.75f * p * p * (-logf(1.0f - p)); \
            } \
            if (pos) { \
                const float aw  = ax2_##k - ax1_##k; \
                const float ah  = ay2_##k - ay1_##k; \
                const float acx = ax1_##k + 0.5f * aw; \
                const float acy = ay1_##k + 0.5f * ah; \
                const float4 ag = s_raw[ba]; \
                const float4 r  = *reinterpret_cast<const float4*>( \
                                      yreg + ((size_t)b * A_N + a) * 4); \
                float gw = fmaxf(ag.z, 1.0f); \
                float gh = fmaxf(ag.w, 1.0f); \
                float t0 = ((ag.x - acx) / aw) / 0.1f; \
                float t1 = ((ag.y - acy) / ah) / 0.1f; \
                float t2 = logf(gw / aw) / 0.2f; \
                float t3 = logf(gh / ah) / 0.2f; \
                float d0 = fabsf(t0 - r.x); \
                float d1 = fabsf(t1 - r.y); \
                float d2 = fabsf(t2 - r.z); \
                float d3 = fabsf(t3 - r.w); \
                const float beta = 1.0f / 9.0f; \
                const float hb   = 0.5f / 9.0f; \
                regv += (d0 <= beta) ? 4.5f * d0 * d0 : d0 - hb; \
                regv += (d1 <= beta) ? 4.5f * d1 * d1 : d1 - hb; \
                regv += (d2 <= beta) ? 4.5f * d2 * d2 : d2 - hb; \
                regv += (d3 <= beta) ? 4.5f * d3 * d3 : d3 - hb; \
            } \
        } }
    K_LIST(TAIL)
#undef TAIL

    // ---- wave (64) reduction, then block reduction, write partials ----
    for (int off = 32; off > 0; off >>= 1) {
        clsv += __shfl_down(clsv, off);
        regv += __shfl_down(regv, off);
        posn += __shfl_down(posn, off);
    }
    const int wid = tid >> 6;
    if ((tid & 63) == 0) {
        s_rc[wid] = clsv; s_rr[wid] = regv; s_rp[wid] = posn;
    }
    __syncthreads();
    if (tid == 0) {
        int idx = b * GX + blockIdx.x;
        ws_cls[idx] = s_rc[0] + s_rc[1] + s_rc[2] + s_rc[3];
        ws_reg[idx] = s_rr[0] + s_rr[1] + s_rr[2] + s_rr[3];
        ws_pos[idx] = s_rp[0] + s_rp[1] + s_rp[2] + s_rp[3];
    }
}

// ---------------------------------------------------------------------------
// Finalize: one wave per image reduces GX partials, normalizes, batch mean.
// ---------------------------------------------------------------------------
__global__ __launch_bounds__(512) void retina_final(
    const float* __restrict__ ws_cls,
    const float* __restrict__ ws_reg,
    const int*   __restrict__ ws_pos,
    float* __restrict__ out)
{
    __shared__ float s_c[B_N], s_r[B_N];
    const int tid  = threadIdx.x;
    const int img  = tid >> 6;          // 8 waves, one image each
    const int lane = tid & 63;

    float c = 0.0f, r = 0.0f;
    int   np = 0;
    for (int j = lane; j < GX; j += 64) {
        int idx = img * GX + j;
        c  += ws_cls[idx];
        r  += ws_reg[idx];
        np += ws_pos[idx];
    }
    for (int off = 32; off > 0; off >>= 1) {
        c  += __shfl_down(c, off);
        r  += __shfl_down(r, off);
        np += __shfl_down(np, off);
    }
    if (lane == 0) {
        float fnp = (float)np;
        s_c[img] = c / fmaxf(fnp, 1.0f);
        s_r[img] = (np > 0) ? r / fmaxf(fnp * 4.0f, 1.0f) : 0.0f;
    }
    __syncthreads();
    if (tid == 0) {
        float cc = 0.0f, rr = 0.0f;
        #pragma unroll
        for (int i = 0; i < B_N; ++i) { cc += s_c[i]; rr += s_r[i]; }
        out[0] = cc * (1.0f / (float)B_N);
        out[1] = rr * (1.0f / (float)B_N);
    }
}

extern "C" void kernel_launch(void* const* d_in, const int* in_sizes, int n_in,
                              void* d_out, int out_size, void* d_ws, size_t ws_size,
                              hipStream_t stream)
{
    const float* yt      = (const float*)d_in[0];  // y_true_tmp   (8,64,5)
    const float* ycls    = (const float*)d_in[1];  // y_classifs   (8,120000,1)
    const float* yreg    = (const float*)d_in[2];  // y_regressions(8,120000,4)
    const float* anchors = (const float*)d_in[3];  // anchors      (1,120000,4)

    float* ws_cls = (float*)d_ws;
    float* ws_reg = ws_cls + B_N * GX;
    int*   ws_pos = (int*)(ws_reg + B_N * GX);

    dim3 grid(GX, B_N);
    retina_main<<<grid, TPB, 0, stream>>>(yt, ycls, yreg, anchors,
                                          ws_cls, ws_reg, ws_pos);
    retina_final<<<1, 512, 0, stream>>>(ws_cls, ws_reg, ws_pos, (float*)d_out);
}

// Round 8
// 91.806 us; speedup vs baseline: 1.0447x; 1.0447x over previous
//
#include <hip/hip_runtime.h>

#define A_N 120000
#define B_N 8
#define M_N 64
#define APT 2                       // anchors per thread (occupancy >> ILP here)
#define TPB 256
#define GX  ((A_N + TPB*APT - 1) / (TPB*APT))   // 235 blocks in x

#define K_LIST(X) X(0) X(1)

// ---------------------------------------------------------------------------
// Main kernel: each thread owns 2 anchors (strided by TPB for coalescing).
// IoU-argmax over the valid GT prefix; iou tracked directly via fast rcp
// (v_rcp_f32, ~1 ulp) -> shortest possible loop body and carried chain.
// ---------------------------------------------------------------------------
__global__ __launch_bounds__(TPB, 4) void retina_main(
    const float* __restrict__ yt,       // (B, M, 5)  cx,cy,w,h,label
    const float* __restrict__ ycls,     // (B, A, 1)
    const float* __restrict__ yreg,     // (B, A, 4)
    const float* __restrict__ anchors,  // (A, 4)     x1,y1,x2,y2
    float* __restrict__ ws_cls,         // [B*GX] partial cls sums
    float* __restrict__ ws_reg,         // [B*GX] partial reg sums
    int*   __restrict__ ws_pos)         // [B*GX] partial pos counts
{
    __shared__ float4 s_box[M_N];   // gt corners
    __shared__ float4 s_raw[M_N];   // raw cx,cy,w,h
    __shared__ float  s_lab[M_N];   // label
    __shared__ float  s_rc[4], s_rr[4];
    __shared__ int    s_rp[4];
    __shared__ int    s_ngt;

    const int b   = blockIdx.y;
    const int tid = threadIdx.x;
    const int a0  = blockIdx.x * (TPB * APT) + tid;   // + k*TPB

    if (tid < M_N) {                 // exactly wave 0, all 64 lanes active
        const float* g = yt + (b * M_N + tid) * 5;
        float cx = g[0], cy = g[1], w = g[2], h = g[3], lab = g[4];
        s_box[tid] = make_float4(cx - 0.5f * w, cy - 0.5f * h,
                                 cx + 0.5f * w, cy + 0.5f * h);
        s_raw[tid] = make_float4(cx, cy, w, h);
        s_lab[tid] = lab;
        // valid GTs are a prefix; count them (wave-uniform loop bound)
        unsigned long long mv = __ballot(lab != -1.0f);
        if (tid == 0) s_ngt = (int)__popcll(mv);
    }
    __syncthreads();
    const int ngt = s_ngt;           // >= 1 always; loop never touches invalid GTs

    // ---- per-anchor state: named scalars only ----
#define DECL(k) float ax1_##k, ay1_##k, ax2_##k, ay2_##k, sa_##k, pp_##k, \
                      bio_##k; int ba_##k;
    K_LIST(DECL)
#undef DECL

#define INIT(k) { \
        int a  = a0 + (k) * TPB; \
        int ac = (a < A_N) ? a : (A_N - 1); \
        float4 an = *reinterpret_cast<const float4*>(anchors + (size_t)ac * 4); \
        ax1_##k = an.x; ay1_##k = an.y; ax2_##k = an.z; ay2_##k = an.w; \
        sa_##k  = (an.z - an.x) * (an.w - an.y); \
        pp_##k  = ycls[(size_t)b * A_N + ac]; \
        bio_##k = -1.0f; ba_##k = 0; }
    K_LIST(INIT)
#undef INIT

    // ---- inner loop over valid GT prefix ----
    #pragma unroll 8
    for (int g = 0; g < ngt; ++g) {
        const float4 gb = s_box[g];
        const float  ga = (gb.z - gb.x) * (gb.w - gb.y);   // shared across APT
#define STEP(k) { \
        float w = fminf(ax2_##k, gb.z) - fmaxf(ax1_##k, gb.x); \
        float h = fminf(ay2_##k, gb.w) - fmaxf(ay1_##k, gb.y); \
        float inter = fmaxf(w, 0.0f) * fmaxf(h, 0.0f); \
        float denom = (sa_##k + ga) - inter; \
        float iou = inter * __builtin_amdgcn_rcpf(denom); \
        bool better = iou > bio_##k;      /* strict > keeps FIRST max */ \
        bio_##k = better ? iou : bio_##k; \
        ba_##k  = better ? g   : ba_##k; }
        K_LIST(STEP)
#undef STEP
    }

    // ---- per-anchor tail: focal cls + smooth-L1 reg ----
    float clsv = 0.0f, regv = 0.0f;
    int   posn = 0;
#define TAIL(k) { \
        int a = a0 + (k) * TPB; \
        if (a < A_N) { \
            const bool pos = (bio_##k >= 0.5f); \
            const bool neg = (bio_##k <  0.4f); \
            posn += pos ? 1 : 0; \
            const float p = pp_##k; \
            float target; \
            if (pos) { \
                int alab = (int)s_lab[ba_##k]; \
                target = (alab == 0) ? 1.0f : 0.0f; \
            } else { \
                target = neg ? 0.0f : -1.0f; \
            } \
            if (target == 1.0f) { \
                float fw = 1.0f - p; \
                clsv += 0.25f * fw * fw * (-logf(p)); \
            } else if (target == 0.0f) { \
                clsv += 0.75f * p * p * (-logf(1.0f - p)); \
            } \
            if (pos) { \
                const float aw  = ax2_##k - ax1_##k; \
                const float ah  = ay2_##k - ay1_##k; \
                const float acx = ax1_##k + 0.5f * aw; \
                const float acy = ay1_##k + 0.5f * ah; \
                const float4 ag = s_raw[ba_##k]; \
                const float4 r  = *reinterpret_cast<const float4*>( \
                                      yreg + ((size_t)b * A_N + a) * 4); \
                float gw = fmaxf(ag.z, 1.0f); \
                float gh = fmaxf(ag.w, 1.0f); \
                float t0 = ((ag.x - acx) / aw) / 0.1f; \
                float t1 = ((ag.y - acy) / ah) / 0.1f; \
                float t2 = logf(gw / aw) / 0.2f; \
                float t3 = logf(gh / ah) / 0.2f; \
                float d0 = fabsf(t0 - r.x); \
                float d1 = fabsf(t1 - r.y); \
                float d2 = fabsf(t2 - r.z); \
                float d3 = fabsf(t3 - r.w); \
                const float beta = 1.0f / 9.0f; \
                const float hb   = 0.5f / 9.0f; \
                regv += (d0 <= beta) ? 4.5f * d0 * d0 : d0 - hb; \
                regv += (d1 <= beta) ? 4.5f * d1 * d1 : d1 - hb; \
                regv += (d2 <= beta) ? 4.5f * d2 * d2 : d2 - hb; \
                regv += (d3 <= beta) ? 4.5f * d3 * d3 : d3 - hb; \
            } \
        } }
    K_LIST(TAIL)
#undef TAIL

    // ---- wave (64) reduction, then block reduction, write partials ----
    for (int off = 32; off > 0; off >>= 1) {
        clsv += __shfl_down(clsv, off);
        regv += __shfl_down(regv, off);
        posn += __shfl_down(posn, off);
    }
    const int wid = tid >> 6;
    if ((tid & 63) == 0) {
        s_rc[wid] = clsv; s_rr[wid] = regv; s_rp[wid] = posn;
    }
    __syncthreads();
    if (tid == 0) {
        int idx = b * GX + blockIdx.x;
        ws_cls[idx] = s_rc[0] + s_rc[1] + s_rc[2] + s_rc[3];
        ws_reg[idx] = s_rr[0] + s_rr[1] + s_rr[2] + s_rr[3];
        ws_pos[idx] = s_rp[0] + s_rp[1] + s_rp[2] + s_rp[3];
    }
}

// ---------------------------------------------------------------------------
// Finalize: one wave per image reduces GX partials, normalizes, batch mean.
// ---------------------------------------------------------------------------
__global__ __launch_bounds__(512) void retina_final(
    const float* __restrict__ ws_cls,
    const float* __restrict__ ws_reg,
    const int*   __restrict__ ws_pos,
    float* __restrict__ out)
{
    __shared__ float s_c[B_N], s_r[B_N];
    const int tid  = threadIdx.x;
    const int img  = tid >> 6;          // 8 waves, one image each
    const int lane = tid & 63;

    float c = 0.0f, r = 0.0f;
    int   np = 0;
    for (int j = lane; j < GX; j += 64) {
        int idx = img * GX + j;
        c  += ws_cls[idx];
        r  += ws_reg[idx];
        np += ws_pos[idx];
    }
    for (int off = 32; off > 0; off >>= 1) {
        c  += __shfl_down(c, off);
        r  += __shfl_down(r, off);
        np += __shfl_down(np, off);
    }
    if (lane == 0) {
        float fnp = (float)np;
        s_c[img] = c / fmaxf(fnp, 1.0f);
        s_r[img] = (np > 0) ? r / fmaxf(fnp * 4.0f, 1.0f) : 0.0f;
    }
    __syncthreads();
    if (tid == 0) {
        float cc = 0.0f, rr = 0.0f;
        #pragma unroll
        for (int i = 0; i < B_N; ++i) { cc += s_c[i]; rr += s_r[i]; }
        out[0] = cc * (1.0f / (float)B_N);
        out[1] = rr * (1.0f / (float)B_N);
    }
}

extern "C" void kernel_launch(void* const* d_in, const int* in_sizes, int n_in,
                              void* d_out, int out_size, void* d_ws, size_t ws_size,
                              hipStream_t stream)
{
    const float* yt      = (const float*)d_in[0];  // y_true_tmp   (8,64,5)
    const float* ycls    = (const float*)d_in[1];  // y_classifs   (8,120000,1)
    const float* yreg    = (const float*)d_in[2];  // y_regressions(8,120000,4)
    const float* anchors = (const float*)d_in[3];  // anchors      (1,120000,4)

    float* ws_cls = (float*)d_ws;
    float* ws_reg = ws_cls + B_N * GX;
    int*   ws_pos = (int*)(ws_reg + B_N * GX);

    dim3 grid(GX, B_N);
    retina_main<<<grid, TPB, 0, stream>>>(yt, ycls, yreg, anchors,
                                          ws_cls, ws_reg, ws_pos);
    retina_final<<<1, 512, 0, stream>>>(ws_cls, ws_reg, ws_pos, (float*)d_out);
}